// Round 1
// baseline (3872.235 us; speedup 1.0000x reference)
//
#include <hip/hip_runtime.h>
#include <math.h>

namespace {
constexpr int B  = 16;
constexpr int H  = 8;
constexpr int HH = 4;
constexpr int N  = 1024;
constexpr int D  = 64;
constexpr int TQ = 16;                // q rows per block (4 per wave)
constexpr float SCALE = 0.125f;       // 1/sqrt(64)
}

// One block = (b, h, 16 q-rows). Each of the 4 waves owns 4 q-rows end-to-end:
// QK^T -> decay modulation -> softmax -> w write -> PV. Rows are wave-private,
// so no __syncthreads() is needed anywhere.
__global__ __launch_bounds__(256, 2)
void bda_fused(const float* __restrict__ q, const float* __restrict__ k,
               const float* __restrict__ v, const float* __restrict__ sph,
               const float* __restrict__ hop, const float* __restrict__ gam,
               float* __restrict__ out, float* __restrict__ w)
{
    __shared__ float s_e[TQ][N];      // 64 KB: logits, then exp values

    const int tile = blockIdx.x;
    const int h    = blockIdx.y;
    const int b    = blockIdx.z;
    const int n0   = tile * TQ;
    const int tid  = (int)threadIdx.x;
    const int lane = tid & 63;
    const int wv   = tid >> 6;
    const int r0   = wv * 4;          // wave-owned rows: n0+r0 .. n0+r0+3
    const long bh    = (long)b * H + h;
    const long kvbase = bh * N * D;

    const bool is_short = (h < HH);
    float l2g = 0.f, hopv = 0.f;
    if (is_short) {
        float g = 1.0f / (1.0f + expf(-gam[h]));
        l2g  = log2f(g);
        hopv = hop[h];
    }

    // Q rows for this wave (wave-uniform addresses -> broadcast loads, L1-hot)
    const float4* q4_0 = (const float4*)(q + kvbase + (long)(n0 + r0 + 0) * D);
    const float4* q4_1 = (const float4*)(q + kvbase + (long)(n0 + r0 + 1) * D);
    const float4* q4_2 = (const float4*)(q + kvbase + (long)(n0 + r0 + 2) * D);
    const float4* q4_3 = (const float4*)(q + kvbase + (long)(n0 + r0 + 3) * D);
    const float4* k4b  = (const float4*)(k + kvbase);

    const float* sp0 = sph + ((long)b * N + n0 + r0 + 0) * N;
    const float* sp1 = sph + ((long)b * N + n0 + r0 + 1) * N;
    const float* sp2 = sph + ((long)b * N + n0 + r0 + 2) * N;
    const float* sp3 = sph + ((long)b * N + n0 + r0 + 3) * N;

    // ---- Phase 1: logits (4 rows per wave, lanes sweep m) ----
    for (int mt = 0; mt < N / 64; ++mt) {
        const int m = mt * 64 + lane;
        const float4* krow = k4b + (long)m * (D / 4);
        float a0 = 0.f, a1 = 0.f, a2 = 0.f, a3 = 0.f;
        #pragma unroll
        for (int d4 = 0; d4 < D / 4; ++d4) {
            const float4 kv = krow[d4];
            float4 t;
            t = q4_0[d4]; a0 += t.x*kv.x + t.y*kv.y + t.z*kv.z + t.w*kv.w;
            t = q4_1[d4]; a1 += t.x*kv.x + t.y*kv.y + t.z*kv.z + t.w*kv.w;
            t = q4_2[d4]; a2 += t.x*kv.x + t.y*kv.y + t.z*kv.z + t.w*kv.w;
            t = q4_3[d4]; a3 += t.x*kv.x + t.y*kv.y + t.z*kv.z + t.w*kv.w;
        }
        a0 *= SCALE; a1 *= SCALE; a2 *= SCALE; a3 *= SCALE;
        if (is_short) {
            a0 *= exp2f(l2g * fmaxf(sp0[m] - hopv, 0.f));
            a1 *= exp2f(l2g * fmaxf(sp1[m] - hopv, 0.f));
            a2 *= exp2f(l2g * fmaxf(sp2[m] - hopv, 0.f));
            a3 *= exp2f(l2g * fmaxf(sp3[m] - hopv, 0.f));
        }
        s_e[r0 + 0][m] = a0;
        s_e[r0 + 1][m] = a1;
        s_e[r0 + 2][m] = a2;
        s_e[r0 + 3][m] = a3;
    }

    // ---- Phase 2: softmax per row (wave-private), write w ----
    float inv[4];
    #pragma unroll
    for (int rr = 0; rr < 4; ++rr) {
        const int r = r0 + rr;
        float mx = -3.402823466e38f;
        for (int j = 0; j < N / 64; ++j)
            mx = fmaxf(mx, s_e[r][lane + 64 * j]);
        #pragma unroll
        for (int off = 32; off; off >>= 1)
            mx = fmaxf(mx, __shfl_xor(mx, off));
        float sum = 0.f;
        for (int j = 0; j < N / 64; ++j) {
            const float e = expf(s_e[r][lane + 64 * j] - mx);
            s_e[r][lane + 64 * j] = e;
            sum += e;
        }
        #pragma unroll
        for (int off = 32; off; off >>= 1)
            sum += __shfl_xor(sum, off);
        inv[rr] = 1.0f / sum;

        float* wrow = w + (bh * N + (n0 + r)) * (long)N;
        const float iv = inv[rr];
        for (int j = 0; j < N / 64; ++j)
            wrow[lane + 64 * j] = s_e[r][lane + 64 * j] * iv;
    }

    // ---- Phase 3: PV (lanes = d, wave sweeps all m for its 4 rows) ----
    const float* vb = v + kvbase;
    float o0 = 0.f, o1 = 0.f, o2 = 0.f, o3 = 0.f;
    for (int mg = 0; mg < N / 4; ++mg) {
        const int m = mg * 4;
        const float4 e0 = *(const float4*)&s_e[r0 + 0][m];
        const float4 e1 = *(const float4*)&s_e[r0 + 1][m];
        const float4 e2 = *(const float4*)&s_e[r0 + 2][m];
        const float4 e3 = *(const float4*)&s_e[r0 + 3][m];
        const float v0_ = vb[(long)(m + 0) * D + lane];
        const float v1_ = vb[(long)(m + 1) * D + lane];
        const float v2_ = vb[(long)(m + 2) * D + lane];
        const float v3_ = vb[(long)(m + 3) * D + lane];
        o0 += e0.x*v0_ + e0.y*v1_ + e0.z*v2_ + e0.w*v3_;
        o1 += e1.x*v0_ + e1.y*v1_ + e1.z*v2_ + e1.w*v3_;
        o2 += e2.x*v0_ + e2.y*v1_ + e2.z*v2_ + e2.w*v3_;
        o3 += e3.x*v0_ + e3.y*v1_ + e3.z*v2_ + e3.w*v3_;
    }
    out[(bh * N + n0 + r0 + 0) * (long)D + lane] = o0 * inv[0];
    out[(bh * N + n0 + r0 + 1) * (long)D + lane] = o1 * inv[1];
    out[(bh * N + n0 + r0 + 2) * (long)D + lane] = o2 * inv[2];
    out[(bh * N + n0 + r0 + 3) * (long)D + lane] = o3 * inv[3];
}

extern "C" void kernel_launch(void* const* d_in, const int* in_sizes, int n_in,
                              void* d_out, int out_size, void* d_ws, size_t ws_size,
                              hipStream_t stream) {
    const float* q   = (const float*)d_in[0];
    const float* k   = (const float*)d_in[1];
    const float* v   = (const float*)d_in[2];
    const float* sph = (const float*)d_in[3];
    const float* hop = (const float*)d_in[4];
    const float* gam = (const float*)d_in[5];

    float* out = (float*)d_out;                       // (B,H,N,D)
    float* w   = out + (size_t)B * H * N * D;         // (B,H,N,N)

    dim3 grid(N / TQ, H, B);
    bda_fused<<<grid, 256, 0, stream>>>(q, k, v, sph, hop, gam, out, w);
}